// Round 7
// baseline (137.917 us; speedup 1.0000x reference)
//
#include <hip/hip_runtime.h>
#include <hip/hip_bf16.h>

typedef unsigned short u16;
typedef __bf16 bf16x8 __attribute__((ext_vector_type(8)));
typedef float f32x4 __attribute__((ext_vector_type(4)));

#define DEVINL __device__ __forceinline__

static constexpr int Bc = 8, Tc = 2048;

DEVINL u16 f2bf(float f) {
  unsigned u = __builtin_bit_cast(unsigned, f);
  unsigned r = u + 0x7fffu + ((u >> 16) & 1u);   // RNE
  return (u16)(r >> 16);
}
DEVINL float bf2f(u16 h) {
  unsigned u = ((unsigned)h) << 16;
  return __builtin_bit_cast(float, u);
}

// swizzled LDS read of 8 contiguous bf16 from a [R][64] bf16 tile.
DEVINL bf16x8 lds_ld8(const u16* p, int row, int col) {
  return *(const bf16x8*)&p[row * 64 + (col ^ ((row & 7) << 3))];
}

// ---------------------------------------------------------------------------
// Kernel 0: wt_{hi,lo}[c][k] = split(W_{c/64}[k][c%64]), c in [0,192)
// ---------------------------------------------------------------------------
__global__ __launch_bounds__(256) void build_wt(const float* __restrict__ Wk,
                                                const float* __restrict__ Wq,
                                                const float* __restrict__ Wv,
                                                u16* __restrict__ wt_hi,
                                                u16* __restrict__ wt_lo) {
  int idx = blockIdx.x * 256 + threadIdx.x;      // 192*1024
  int c = idx >> 10, k = idx & 1023;
  const float* W = (c < 64) ? Wk : (c < 128 ? Wq : Wv);
  float f = W[k * 64 + (c & 63)];
  u16 h = f2bf(f);
  wt_hi[idx] = h;
  wt_lo[idx] = f2bf(f - bf2f(h));
}

// ---------------------------------------------------------------------------
// Kernel 1: fused QKV projection, hi/lo split, IN-BLOCK K-SPLIT x2.
// 512 blocks x 512 thr (8 waves). Wave-group g (waves 4g..4g+3) handles
// K-chunks g*8..g*8+7 over the same 32 rows x 192 cols; cross-group reduce
// via LDS at the end; group 0 writes the epilogue.
// V written TRANSPOSED [b][d][t].
// ---------------------------------------------------------------------------
__global__ __launch_bounds__(512, 4) void proj_kernel(const float* __restrict__ x,
                                                      const u16* __restrict__ wt_hi,
                                                      const u16* __restrict__ wt_lo,
                                                      u16* __restrict__ kb_h, u16* __restrict__ kb_l,
                                                      u16* __restrict__ qb_h, u16* __restrict__ qb_l,
                                                      u16* __restrict__ vt) {
  __shared__ u16 xh[2][2][32 * 64];      // [group][dbuf]
  __shared__ u16 xl[2][2][32 * 64];
  __shared__ f32x4 red[4][64][6];        // 24KB cross-group reduce buffer
  const int t = threadIdx.x;
  const int w = t >> 6, lane = t & 63;
  const int g = w >> 2, wg = w & 3;      // K-group, wave-in-group
  const int l16 = lane & 15, lhi = lane >> 4;
  const int rb = blockIdx.x * 32;
  const int cb = wg * 48;
  const int tg = t & 255;                // thread-in-group
  const int sr = tg >> 3, sc = (tg & 7) * 8;
  const f32x4* xrow = (const f32x4*)(x + (size_t)(rb + sr) * 1024 + g * 512 + sc);
  // local chunk ch (0..7) -> xrow + ch*16 (and +1); global chunk = g*8+ch

  f32x4 acc[2][3];
#pragma unroll
  for (int a = 0; a < 2; ++a)
#pragma unroll
    for (int c = 0; c < 3; ++c) acc[a][c] = (f32x4){0.f, 0.f, 0.f, 0.f};

#define CVT_STORE(S, F0, F1)                                                   \
  {                                                                            \
    union { u16 u[8]; uint4 v; } ph_, pl_;                                     \
    _Pragma("unroll") for (int j = 0; j < 4; ++j) {                            \
      u16 h0 = f2bf((F0)[j]); ph_.u[j] = h0; pl_.u[j] = f2bf((F0)[j] - bf2f(h0)); \
      u16 h1 = f2bf((F1)[j]); ph_.u[4+j] = h1; pl_.u[4+j] = f2bf((F1)[j] - bf2f(h1)); \
    }                                                                          \
    *(uint4*)&xh[g][S][sr * 64 + (sc ^ ((sr & 7) << 3))] = ph_.v;              \
    *(uint4*)&xl[g][S][sr * 64 + (sc ^ ((sr & 7) << 3))] = pl_.v;              \
  }

#define COMPUTE(S, CHL)                                                        \
  {                                                                            \
    bf16x8 Bh_[2][3], Bl_[2][3];                                               \
    _Pragma("unroll") for (int kk = 0; kk < 2; ++kk)                           \
      _Pragma("unroll") for (int tc = 0; tc < 3; ++tc) {                       \
        size_t wi = (size_t)(cb + tc * 16 + l16) * 1024 + (g * 8 + (CHL)) * 64 + kk * 32 + lhi * 8; \
        Bh_[kk][tc] = *(const bf16x8*)&wt_hi[wi];                              \
        Bl_[kk][tc] = *(const bf16x8*)&wt_lo[wi];                              \
      }                                                                        \
    _Pragma("unroll") for (int kk = 0; kk < 2; ++kk) {                         \
      bf16x8 a0h = lds_ld8(xh[g][S], l16, kk * 32 + lhi * 8);                  \
      bf16x8 a0l = lds_ld8(xl[g][S], l16, kk * 32 + lhi * 8);                  \
      bf16x8 a1h = lds_ld8(xh[g][S], 16 + l16, kk * 32 + lhi * 8);             \
      bf16x8 a1l = lds_ld8(xl[g][S], 16 + l16, kk * 32 + lhi * 8);             \
      _Pragma("unroll") for (int tc = 0; tc < 3; ++tc) {                       \
        acc[0][tc] = __builtin_amdgcn_mfma_f32_16x16x32_bf16(a0h, Bh_[kk][tc], acc[0][tc], 0, 0, 0); \
        acc[0][tc] = __builtin_amdgcn_mfma_f32_16x16x32_bf16(a0h, Bl_[kk][tc], acc[0][tc], 0, 0, 0); \
        acc[0][tc] = __builtin_amdgcn_mfma_f32_16x16x32_bf16(a0l, Bh_[kk][tc], acc[0][tc], 0, 0, 0); \
        acc[1][tc] = __builtin_amdgcn_mfma_f32_16x16x32_bf16(a1h, Bh_[kk][tc], acc[1][tc], 0, 0, 0); \
        acc[1][tc] = __builtin_amdgcn_mfma_f32_16x16x32_bf16(a1h, Bl_[kk][tc], acc[1][tc], 0, 0, 0); \
        acc[1][tc] = __builtin_amdgcn_mfma_f32_16x16x32_bf16(a1l, Bh_[kk][tc], acc[1][tc], 0, 0, 0); \
      }                                                                        \
    }                                                                          \
  }

  // prologue: 2-deep prefetch (non-temporal: x is read-once)
  f32x4 A0 = __builtin_nontemporal_load(xrow);
  f32x4 A1 = __builtin_nontemporal_load(xrow + 1);
  f32x4 B0 = __builtin_nontemporal_load(xrow + 16);
  f32x4 B1 = __builtin_nontemporal_load(xrow + 17);
  CVT_STORE(0, A0, A1);
  __syncthreads();

  for (int i = 0; i < 4; ++i) {
    const int ch = 2 * i;
    if (ch + 2 < 8) {
      A0 = __builtin_nontemporal_load(xrow + (ch + 2) * 16);
      A1 = __builtin_nontemporal_load(xrow + (ch + 2) * 16 + 1);
    }
    COMPUTE(0, ch);
    CVT_STORE(1, B0, B1);
    __syncthreads();
    if (ch + 3 < 8) {
      B0 = __builtin_nontemporal_load(xrow + (ch + 3) * 16);
      B1 = __builtin_nontemporal_load(xrow + (ch + 3) * 16 + 1);
    }
    COMPUTE(1, ch + 1);
    if (ch + 2 < 8) { CVT_STORE(0, A0, A1); __syncthreads(); }
  }
#undef CVT_STORE
#undef COMPUTE

  // cross-group reduce: group 1 publishes acc, group 0 adds + epilogue
  if (g == 1) {
#pragma unroll
    for (int a = 0; a < 2; ++a)
#pragma unroll
      for (int c = 0; c < 3; ++c) red[wg][lane][a * 3 + c] = acc[a][c];
  }
  __syncthreads();
  if (g == 0) {
#pragma unroll
    for (int a = 0; a < 2; ++a)
#pragma unroll
      for (int c = 0; c < 3; ++c) acc[a][c] += red[wg][lane][a * 3 + c];

#pragma unroll
    for (int ri = 0; ri < 2; ++ri) {
#pragma unroll
      for (int tc = 0; tc < 3; ++tc) {
        int gc = cb + tc * 16 + l16;
        int cc = gc & 63;
        int row = rb + ri * 16 + lhi * 4;
#pragma unroll
        for (int i = 0; i < 4; ++i) {
          float f = acc[ri][tc][i];
          int r = row + i;
          u16 h = f2bf(f);
          if (gc < 64) {
            size_t off = (size_t)r * 64 + cc;
            kb_h[off] = h; kb_l[off] = f2bf(f - bf2f(h));
          } else if (gc < 128) {
            size_t off = (size_t)r * 64 + cc;
            qb_h[off] = h; qb_l[off] = f2bf(f - bf2f(h));
          } else {
            int bb = r >> 11, tp = r & 2047;
            vt[((size_t)bb * 64 + cc) * 2048 + tp] = h;
          }
        }
      }
    }
  }
}

// ---------------------------------------------------------------------------
// Kernel 2: causal flash attention, barrier-free, KV-chunk 256.
// 288 units/batch x 8 = 2304 blocks x 1 wave. Unit order: 224 full units
// (nt=4, j>=8c+8, j desc per c) first, then 64 edge units (diag, nt<=4).
// All units write (O,m,l) partials; combine merges up to 8.
// ---------------------------------------------------------------------------
__global__ __launch_bounds__(64, 2) void attn_kernel(const u16* __restrict__ qb_h,
                                                     const u16* __restrict__ qb_l,
                                                     const u16* __restrict__ kb_h,
                                                     const u16* __restrict__ kb_l,
                                                     const u16* __restrict__ vt,
                                                     float* __restrict__ po,
                                                     float* __restrict__ pml) {
  __shared__ u16 p_l[2][1024];           // per-rowset P tile (16x64, swizzled)

  const int t = threadIdx.x;             // one wave
  const int l16 = t & 15, lhi = t >> 4;
  const int u = blockIdx.x >> 3, b = blockIdx.x & 7;

  int c, j;
  if (u < 224) {                         // full units: c in 0..6
    int rem = u; c = 0;
    while (rem >= 56 - 8 * c) { rem -= 56 - 8 * c; ++c; }
    j = 63 - rem;
  } else {                               // edge (diagonal) units
    int e = u - 224; c = e >> 3; j = 8 * c + 7 - (e & 7);
  }

  const int kv0 = c << 8;
  const int prefix = j * 32 + 32;
  const int kv_end = (prefix < kv0 + 256) ? prefix : (kv0 + 256);
  const int nt = (kv_end - kv0 + 63) >> 6;
  const bool diag = (kv_end == prefix);

  const size_t qrow = (size_t)b * 2048 + j * 32;

  // Q fragments straight from global: lane l16 = q row, 16B contiguous cols
  bf16x8 aqh[2][2], aql[2][2];           // [rowset][kk]
#pragma unroll
  for (int rs = 0; rs < 2; ++rs)
#pragma unroll
    for (int kk = 0; kk < 2; ++kk) {
      size_t qo = (qrow + rs * 16 + l16) * 64 + kk * 32 + lhi * 8;
      aqh[rs][kk] = *(const bf16x8*)(qb_h + qo);
      aql[rs][kk] = *(const bf16x8*)(qb_l + qo);
    }

  f32x4 o[2][4];
  float m_r[2][4], l_r[2][4];
#pragma unroll
  for (int rs = 0; rs < 2; ++rs)
#pragma unroll
    for (int i = 0; i < 4; ++i) {
      o[rs][i] = (f32x4){0.f, 0.f, 0.f, 0.f};
      m_r[rs][i] = -3.0e38f; l_r[rs][i] = 0.f;
    }

  for (int tk = 0; tk < nt; ++tk) {
    const int kvb = kv0 + tk * 64;
    const size_t kbase = ((size_t)b * 2048 + kvb) * 64;

    // S = Q K^T: K frags loaded per-t4 (transient regs)
    f32x4 sa[2][4];
#pragma unroll
    for (int t4 = 0; t4 < 4; ++t4) {
      size_t kr = kbase + (size_t)(t4 * 16 + l16) * 64 + lhi * 8;
      bf16x8 kh0 = *(const bf16x8*)(kb_h + kr);
      bf16x8 kh1 = *(const bf16x8*)(kb_h + kr + 32);
      bf16x8 kl0 = *(const bf16x8*)(kb_l + kr);
      bf16x8 kl1 = *(const bf16x8*)(kb_l + kr + 32);
#pragma unroll
      for (int rs = 0; rs < 2; ++rs) {
        f32x4 s = (f32x4){0.f, 0.f, 0.f, 0.f};
        s = __builtin_amdgcn_mfma_f32_16x16x32_bf16(aqh[rs][0], kh0, s, 0, 0, 0);
        s = __builtin_amdgcn_mfma_f32_16x16x32_bf16(aqh[rs][0], kl0, s, 0, 0, 0);
        s = __builtin_amdgcn_mfma_f32_16x16x32_bf16(aql[rs][0], kh0, s, 0, 0, 0);
        s = __builtin_amdgcn_mfma_f32_16x16x32_bf16(aqh[rs][1], kh1, s, 0, 0, 0);
        s = __builtin_amdgcn_mfma_f32_16x16x32_bf16(aqh[rs][1], kl1, s, 0, 0, 0);
        s = __builtin_amdgcn_mfma_f32_16x16x32_bf16(aql[rs][1], kh1, s, 0, 0, 0);
        sa[rs][t4] = s;
      }
    }

    // causal mask; only the diagonal unit's last tile
    if (diag && tk == nt - 1) {
#pragma unroll
      for (int rs = 0; rs < 2; ++rs) {
        int qr = j * 32 + rs * 16 + lhi * 4;
#pragma unroll
        for (int t4 = 0; t4 < 4; ++t4) {
          int col = kvb + t4 * 16 + l16;
#pragma unroll
          for (int i = 0; i < 4; ++i)
            if (col > qr + i) sa[rs][t4][i] = -1e30f;
        }
      }
    }

    // online softmax for both rowsets; P -> bf16 -> wave-private LDS
#pragma unroll
    for (int rs = 0; rs < 2; ++rs) {
      float pf[4][4];
#pragma unroll
      for (int i = 0; i < 4; ++i) {
        float tm = fmaxf(fmaxf(sa[rs][0][i], sa[rs][1][i]), fmaxf(sa[rs][2][i], sa[rs][3][i]));
#pragma unroll
        for (int d = 1; d < 16; d <<= 1) tm = fmaxf(tm, __shfl_xor(tm, d));
        float mn = fmaxf(m_r[rs][i], tm);
        float scl = __expf(m_r[rs][i] - mn);
        float rsum = 0.f;
#pragma unroll
        for (int t4 = 0; t4 < 4; ++t4) {
          float p = __expf(sa[rs][t4][i] - mn);
          pf[t4][i] = p;
          rsum += p;
        }
#pragma unroll
        for (int d = 1; d < 16; d <<= 1) rsum += __shfl_xor(rsum, d);
        l_r[rs][i] = l_r[rs][i] * scl + rsum;
        m_r[rs][i] = mn;
#pragma unroll
        for (int t4 = 0; t4 < 4; ++t4) o[rs][t4][i] *= scl;
      }
      u16* pw = (u16*)p_l[rs];
#pragma unroll
      for (int i = 0; i < 4; ++i) {
        int rr = lhi * 4 + i;
#pragma unroll
        for (int t4 = 0; t4 < 4; ++t4) {
          int col = t4 * 16 + l16;
          pw[rr * 64 + (col ^ ((rr & 7) << 3))] = f2bf(pf[t4][i]);
        }
      }
    }

    // PV joint over rowsets: V frags transient per-kk, shared by both rs
#pragma unroll
    for (int kk = 0; kk < 2; ++kk) {
      bf16x8 vk[4];
#pragma unroll
      for (int t4 = 0; t4 < 4; ++t4)
        vk[t4] = *(const bf16x8*)(vt + ((size_t)b * 64 + t4 * 16 + l16) * 2048 + kvb + kk * 32 + lhi * 8);
#pragma unroll
      for (int rs = 0; rs < 2; ++rs) {
        bf16x8 ap = lds_ld8((u16*)p_l[rs], l16, kk * 32 + lhi * 8);
#pragma unroll
        for (int t4 = 0; t4 < 4; ++t4)
          o[rs][t4] = __builtin_amdgcn_mfma_f32_16x16x32_bf16(ap, vk[t4], o[rs][t4], 0, 0, 0);
      }
    }
  }

  // write partials (all units); slot = blockIdx.x
  const int slot = blockIdx.x;
  float* pou = po + (size_t)slot * 2048;
#pragma unroll
  for (int rs = 0; rs < 2; ++rs)
#pragma unroll
    for (int t4 = 0; t4 < 4; ++t4) {
      int col = t4 * 16 + l16;
#pragma unroll
      for (int i = 0; i < 4; ++i)
        pou[(rs * 16 + lhi * 4 + i) * 64 + col] = o[rs][t4][i];
    }
  if (l16 == 0) {
#pragma unroll
    for (int rs = 0; rs < 2; ++rs)
#pragma unroll
      for (int i = 0; i < 4; ++i) {
        int r = rs * 16 + lhi * 4 + i;
        pml[slot * 64 + r]      = m_r[rs][i];
        pml[slot * 64 + 32 + r] = l_r[rs][i];
      }
  }
}

// ---------------------------------------------------------------------------
// Kernel 3: merge up to 8 KV-chunk partials. Grid 512 = 64 j x 8 b, 256 thr.
// ---------------------------------------------------------------------------
DEVINL int unit_of(int c, int j) {
  return (j >= 8 * c + 8) ? (c * (60 - 4 * c) + 63 - j)
                          : (224 + c * 8 + 7 - (j - 8 * c));
}

__global__ __launch_bounds__(256) void combine_kernel(const float* __restrict__ po,
                                                      const float* __restrict__ pml,
                                                      float* __restrict__ out) {
  const int b = blockIdx.x & 7, j = blockIdx.x >> 3;
  const int nu = (j >> 3) + 1;
  int slots[8];
#pragma unroll
  for (int c = 0; c < 8; ++c) slots[c] = (c < nu) ? (unit_of(c, j) * 8 + b) : 0;
  float* og = out + ((size_t)b * 2048 + j * 32) * 64;
#pragma unroll
  for (int k = 0; k < 8; ++k) {
    int e = k * 256 + threadIdx.x;
    int r = e >> 6;
    float M = -3.0e38f;
#pragma unroll
    for (int c = 0; c < 8; ++c)
      if (c < nu) M = fmaxf(M, pml[slots[c] * 64 + r]);
    float num = 0.f, den = 0.f;
#pragma unroll
    for (int c = 0; c < 8; ++c)
      if (c < nu) {
        float a = __expf(pml[slots[c] * 64 + r] - M);
        num += po[(size_t)slots[c] * 2048 + e] * a;
        den += pml[slots[c] * 64 + 32 + r] * a;
      }
    og[e] = num / den;
  }
}

// ---------------------------------------------------------------------------
extern "C" void kernel_launch(void* const* d_in, const int* in_sizes, int n_in,
                              void* d_out, int out_size, void* d_ws, size_t ws_size,
                              hipStream_t stream) {
  const float* x  = (const float*)d_in[0];
  const float* Wk = (const float*)d_in[1];
  const float* Wq = (const float*)d_in[2];
  const float* Wv = (const float*)d_in[3];
  float* out = (float*)d_out;

  const size_t QKV = (size_t)Bc * Tc * 64;       // 1,048,576 elems
  char* w = (char*)d_ws;
  u16* kb_h = (u16*)w;               w += QKV * 2;
  u16* kb_l = (u16*)w;               w += QKV * 2;
  u16* qb_h = (u16*)w;               w += QKV * 2;
  u16* qb_l = (u16*)w;               w += QKV * 2;
  u16* vt   = (u16*)w;               w += QKV * 2;
  u16* wt_h = (u16*)w;               w += (size_t)192 * 1024 * 2;
  u16* wt_l = (u16*)w;               w += (size_t)192 * 1024 * 2;
  float* po = (float*)w;             w += (size_t)2304 * 2048 * 4;
  float* pml = (float*)w;            w += (size_t)2304 * 64 * 4;

  build_wt<<<768, 256, 0, stream>>>(Wk, Wq, Wv, wt_h, wt_l);
  proj_kernel<<<512, 512, 0, stream>>>(x, wt_h, wt_l, kb_h, kb_l, qb_h, qb_l, vt);
  attn_kernel<<<2304, 64, 0, stream>>>(qb_h, qb_l, kb_h, kb_l, vt, po, pml);
  combine_kernel<<<512, 256, 0, stream>>>(po, pml, out);
}

// Round 8
// 98.078 us; speedup vs baseline: 1.4062x; 1.4062x over previous
//
#include <hip/hip_runtime.h>
#include <hip/hip_bf16.h>

typedef unsigned short u16;
typedef __bf16 bf16x8 __attribute__((ext_vector_type(8)));
typedef _Float16 f16x8 __attribute__((ext_vector_type(8)));
typedef float f32x4 __attribute__((ext_vector_type(4)));

#define DEVINL __device__ __forceinline__

static constexpr int Bc = 8, Tc = 2048;

DEVINL u16 f2bf(float f) {
  unsigned u = __builtin_bit_cast(unsigned, f);
  unsigned r = u + 0x7fffu + ((u >> 16) & 1u);   // RNE
  return (u16)(r >> 16);
}
DEVINL float bf2f(u16 h) {
  unsigned u = ((unsigned)h) << 16;
  return __builtin_bit_cast(float, u);
}

// swizzled LDS read of 8 contiguous 16-bit elems from a [R][64] tile.
DEVINL bf16x8 lds_ld8(const u16* p, int row, int col) {
  return *(const bf16x8*)&p[row * 64 + (col ^ ((row & 7) << 3))];
}
DEVINL f16x8 lds_ld8h(const u16* p, int row, int col) {
  return *(const f16x8*)&p[row * 64 + (col ^ ((row & 7) << 3))];
}

// ---------------------------------------------------------------------------
// Kernel 0: wtf[c][k] = f16(W_{c/64}[k][c%64]), c in [0,192)
// ---------------------------------------------------------------------------
__global__ __launch_bounds__(256) void build_wt(const float* __restrict__ Wk,
                                                const float* __restrict__ Wq,
                                                const float* __restrict__ Wv,
                                                u16* __restrict__ wtf) {
  int idx = blockIdx.x * 256 + threadIdx.x;      // 192*1024
  int c = idx >> 10, k = idx & 1023;
  const float* W = (c < 64) ? Wk : (c < 128 ? Wq : Wv);
  _Float16 h = (_Float16)W[k * 64 + (c & 63)];
  wtf[idx] = __builtin_bit_cast(u16, h);
}

// ---------------------------------------------------------------------------
// Kernel 1: fused QKV projection, f16-single inputs (x, W as f16; one MFMA
// per (kk,tc,rowset) -> 12/chunk/wave vs 36 for bf16 hi/lo-triple).
// R6 skeleton: 512 blocks x 256 thr (4 waves; wave = 48 cols x 32 rows),
// NT x loads, per-chunk B-hoist, LDS dbuf. q,k still written hi/lo bf16;
// V written TRANSPOSED [b][d][t] bf16.
// ---------------------------------------------------------------------------
__global__ __launch_bounds__(256, 2) void proj_kernel(const float* __restrict__ x,
                                                      const u16* __restrict__ wtf,
                                                      u16* __restrict__ kb_h, u16* __restrict__ kb_l,
                                                      u16* __restrict__ qb_h, u16* __restrict__ qb_l,
                                                      u16* __restrict__ vt) {
  __shared__ u16 xf[2][32 * 64];
  const int t = threadIdx.x;
  const int w = t >> 6, lane = t & 63;
  const int l16 = lane & 15, lhi = lane >> 4;
  const int rb = blockIdx.x * 32;
  const int cb = w * 48;
  const int sr = t >> 3, sc = (t & 7) * 8;
  const f32x4* xrow = (const f32x4*)(x + (size_t)(rb + sr) * 1024 + sc);
  // chunk ch -> xrow + ch*16 and +1

  f32x4 acc[2][3];
#pragma unroll
  for (int a = 0; a < 2; ++a)
#pragma unroll
    for (int c = 0; c < 3; ++c) acc[a][c] = (f32x4){0.f, 0.f, 0.f, 0.f};

#define CVT_STORE(S, F0, F1)                                                   \
  {                                                                            \
    union { _Float16 h[8]; uint4 v; } p_;                                      \
    _Pragma("unroll") for (int j = 0; j < 4; ++j) {                            \
      p_.h[j] = (_Float16)(F0)[j];                                             \
      p_.h[4 + j] = (_Float16)(F1)[j];                                         \
    }                                                                          \
    *(uint4*)&xf[S][sr * 64 + (sc ^ ((sr & 7) << 3))] = p_.v;                  \
  }

#define COMPUTE(S, CH)                                                         \
  {                                                                            \
    f16x8 Bf_[2][3];                                                           \
    _Pragma("unroll") for (int kk = 0; kk < 2; ++kk)                           \
      _Pragma("unroll") for (int tc = 0; tc < 3; ++tc) {                       \
        size_t wi = (size_t)(cb + tc * 16 + l16) * 1024 + (CH) * 64 + kk * 32 + lhi * 8; \
        Bf_[kk][tc] = *(const f16x8*)&wtf[wi];                                 \
      }                                                                        \
    _Pragma("unroll") for (int kk = 0; kk < 2; ++kk) {                         \
      f16x8 a0 = lds_ld8h(xf[S], l16, kk * 32 + lhi * 8);                      \
      f16x8 a1 = lds_ld8h(xf[S], 16 + l16, kk * 32 + lhi * 8);                 \
      _Pragma("unroll") for (int tc = 0; tc < 3; ++tc) {                       \
        acc[0][tc] = __builtin_amdgcn_mfma_f32_16x16x32_f16(a0, Bf_[kk][tc], acc[0][tc], 0, 0, 0); \
        acc[1][tc] = __builtin_amdgcn_mfma_f32_16x16x32_f16(a1, Bf_[kk][tc], acc[1][tc], 0, 0, 0); \
      }                                                                        \
    }                                                                          \
  }

  // prologue: 2-deep prefetch (non-temporal: x is read-once)
  f32x4 A0 = __builtin_nontemporal_load(xrow);
  f32x4 A1 = __builtin_nontemporal_load(xrow + 1);
  f32x4 B0 = __builtin_nontemporal_load(xrow + 16);
  f32x4 B1 = __builtin_nontemporal_load(xrow + 17);
  CVT_STORE(0, A0, A1);
  __syncthreads();

  for (int i = 0; i < 8; ++i) {
    const int ch = 2 * i;
    if (ch + 2 < 16) {
      A0 = __builtin_nontemporal_load(xrow + (ch + 2) * 16);
      A1 = __builtin_nontemporal_load(xrow + (ch + 2) * 16 + 1);
    }
    COMPUTE(0, ch);
    CVT_STORE(1, B0, B1);
    __syncthreads();
    if (ch + 3 < 16) {
      B0 = __builtin_nontemporal_load(xrow + (ch + 3) * 16);
      B1 = __builtin_nontemporal_load(xrow + (ch + 3) * 16 + 1);
    }
    COMPUTE(1, ch + 1);
    if (ch + 2 < 16) { CVT_STORE(0, A0, A1); __syncthreads(); }
  }
#undef CVT_STORE
#undef COMPUTE

  // epilogue
#pragma unroll
  for (int ri = 0; ri < 2; ++ri) {
#pragma unroll
    for (int tc = 0; tc < 3; ++tc) {
      int gc = cb + tc * 16 + l16;
      int cc = gc & 63;
      int row = rb + ri * 16 + lhi * 4;
#pragma unroll
      for (int i = 0; i < 4; ++i) {
        float f = acc[ri][tc][i];
        int r = row + i;
        u16 h = f2bf(f);
        if (gc < 64) {
          size_t off = (size_t)r * 64 + cc;
          kb_h[off] = h; kb_l[off] = f2bf(f - bf2f(h));
        } else if (gc < 128) {
          size_t off = (size_t)r * 64 + cc;
          qb_h[off] = h; qb_l[off] = f2bf(f - bf2f(h));
        } else {
          int bb = r >> 11, tp = r & 2047;
          vt[((size_t)bb * 64 + cc) * 2048 + tp] = h;
        }
      }
    }
  }
}

// ---------------------------------------------------------------------------
// Kernel 2: causal flash attention, barrier-free, KV-chunk 512.
// (exact R6-measured version: 160 units/batch x 8 = 1280 blocks x 1 wave)
// ---------------------------------------------------------------------------
__global__ __launch_bounds__(64, 2) void attn_kernel(const u16* __restrict__ qb_h,
                                                     const u16* __restrict__ qb_l,
                                                     const u16* __restrict__ kb_h,
                                                     const u16* __restrict__ kb_l,
                                                     const u16* __restrict__ vt,
                                                     float* __restrict__ po,
                                                     float* __restrict__ pml) {
  __shared__ u16 p_l[2][1024];           // per-rowset P tile (16x64, swizzled)

  const int t = threadIdx.x;             // one wave
  const int l16 = t & 15, lhi = t >> 4;
  const int u = blockIdx.x >> 3, b = blockIdx.x & 7;

  int j, c;
  if (u < 64)       { c = 0; j = 63 - u; }
  else if (u < 112) { c = 1; j = 63 - (u - 64); }
  else if (u < 144) { c = 2; j = 63 - (u - 112); }
  else              { c = 3; j = 63 - (u - 144); }

  const int kv0 = c << 9;
  const int prefix = j * 32 + 32;
  const int kv_end = (prefix < kv0 + 512) ? prefix : (kv0 + 512);
  const int nt = (kv_end - kv0 + 63) >> 6;
  const bool diag = (kv_end == prefix);

  const size_t qrow = (size_t)b * 2048 + j * 32;

  // Q fragments straight from global: lane l16 = q row, 16B contiguous cols
  bf16x8 aqh[2][2], aql[2][2];           // [rowset][kk]
#pragma unroll
  for (int rs = 0; rs < 2; ++rs)
#pragma unroll
    for (int kk = 0; kk < 2; ++kk) {
      size_t qo = (qrow + rs * 16 + l16) * 64 + kk * 32 + lhi * 8;
      aqh[rs][kk] = *(const bf16x8*)(qb_h + qo);
      aql[rs][kk] = *(const bf16x8*)(qb_l + qo);
    }

  f32x4 o[2][4];
  float m_r[2][4], l_r[2][4];
#pragma unroll
  for (int rs = 0; rs < 2; ++rs)
#pragma unroll
    for (int i = 0; i < 4; ++i) {
      o[rs][i] = (f32x4){0.f, 0.f, 0.f, 0.f};
      m_r[rs][i] = -3.0e38f; l_r[rs][i] = 0.f;
    }

  for (int tk = 0; tk < nt; ++tk) {
    const int kvb = kv0 + tk * 64;
    const size_t kbase = ((size_t)b * 2048 + kvb) * 64;

    // S = Q K^T: K frags loaded per-t4 (transient regs)
    f32x4 sa[2][4];
#pragma unroll
    for (int t4 = 0; t4 < 4; ++t4) {
      size_t kr = kbase + (size_t)(t4 * 16 + l16) * 64 + lhi * 8;
      bf16x8 kh0 = *(const bf16x8*)(kb_h + kr);
      bf16x8 kh1 = *(const bf16x8*)(kb_h + kr + 32);
      bf16x8 kl0 = *(const bf16x8*)(kb_l + kr);
      bf16x8 kl1 = *(const bf16x8*)(kb_l + kr + 32);
#pragma unroll
      for (int rs = 0; rs < 2; ++rs) {
        f32x4 s = (f32x4){0.f, 0.f, 0.f, 0.f};
        s = __builtin_amdgcn_mfma_f32_16x16x32_bf16(aqh[rs][0], kh0, s, 0, 0, 0);
        s = __builtin_amdgcn_mfma_f32_16x16x32_bf16(aqh[rs][0], kl0, s, 0, 0, 0);
        s = __builtin_amdgcn_mfma_f32_16x16x32_bf16(aql[rs][0], kh0, s, 0, 0, 0);
        s = __builtin_amdgcn_mfma_f32_16x16x32_bf16(aqh[rs][1], kh1, s, 0, 0, 0);
        s = __builtin_amdgcn_mfma_f32_16x16x32_bf16(aqh[rs][1], kl1, s, 0, 0, 0);
        s = __builtin_amdgcn_mfma_f32_16x16x32_bf16(aql[rs][1], kh1, s, 0, 0, 0);
        sa[rs][t4] = s;
      }
    }

    // V fragment loads (consumed in PV; issued before softmax to hide latency)
    bf16x8 vv[4][2];
#pragma unroll
    for (int t4 = 0; t4 < 4; ++t4) {
      size_t vr = ((size_t)b * 64 + t4 * 16 + l16) * 2048 + kvb + lhi * 8;
      vv[t4][0] = *(const bf16x8*)(vt + vr);
      vv[t4][1] = *(const bf16x8*)(vt + vr + 32);
    }

    // causal mask (global indices); only the diagonal unit's last tile
    if (diag && tk == nt - 1) {
#pragma unroll
      for (int rs = 0; rs < 2; ++rs) {
        int qr = j * 32 + rs * 16 + lhi * 4;
#pragma unroll
        for (int t4 = 0; t4 < 4; ++t4) {
          int col = kvb + t4 * 16 + l16;
#pragma unroll
          for (int i = 0; i < 4; ++i)
            if (col > qr + i) sa[rs][t4][i] = -1e30f;
        }
      }
    }

#pragma unroll
    for (int rs = 0; rs < 2; ++rs) {
      // online softmax
      float pf[4][4];
#pragma unroll
      for (int i = 0; i < 4; ++i) {
        float tm = fmaxf(fmaxf(sa[rs][0][i], sa[rs][1][i]), fmaxf(sa[rs][2][i], sa[rs][3][i]));
#pragma unroll
        for (int d = 1; d < 16; d <<= 1) tm = fmaxf(tm, __shfl_xor(tm, d));
        float mn = fmaxf(m_r[rs][i], tm);
        float scl = __expf(m_r[rs][i] - mn);
        float rsum = 0.f;
#pragma unroll
        for (int t4 = 0; t4 < 4; ++t4) {
          float p = __expf(sa[rs][t4][i] - mn);
          pf[t4][i] = p;
          rsum += p;
        }
#pragma unroll
        for (int d = 1; d < 16; d <<= 1) rsum += __shfl_xor(rsum, d);
        l_r[rs][i] = l_r[rs][i] * scl + rsum;
        m_r[rs][i] = mn;
#pragma unroll
        for (int t4 = 0; t4 < 4; ++t4) o[rs][t4][i] *= scl;
      }

      // P -> bf16 -> per-rowset LDS (swizzled, wave-private, no barrier)
      u16* pw = (u16*)p_l[rs];
#pragma unroll
      for (int i = 0; i < 4; ++i) {
        int rr = lhi * 4 + i;
#pragma unroll
        for (int t4 = 0; t4 < 4; ++t4) {
          int col = t4 * 16 + l16;
          pw[rr * 64 + (col ^ ((rr & 7) << 3))] = f2bf(pf[t4][i]);
        }
      }
      // PV
#pragma unroll
      for (int kk = 0; kk < 2; ++kk) {
        bf16x8 ap = lds_ld8(pw, l16, kk * 32 + lhi * 8);
#pragma unroll
        for (int t4 = 0; t4 < 4; ++t4)
          o[rs][t4] = __builtin_amdgcn_mfma_f32_16x16x32_bf16(ap, vv[t4][kk], o[rs][t4], 0, 0, 0);
      }
    }
  }

  // write partials (all units)
  const int slot = blockIdx.x;
  float* pou = po + (size_t)slot * 2048;
#pragma unroll
  for (int rs = 0; rs < 2; ++rs)
#pragma unroll
    for (int t4 = 0; t4 < 4; ++t4) {
      int col = t4 * 16 + l16;
#pragma unroll
      for (int i = 0; i < 4; ++i)
        pou[(rs * 16 + lhi * 4 + i) * 64 + col] = o[rs][t4][i];
    }
  if (l16 == 0) {
#pragma unroll
    for (int rs = 0; rs < 2; ++rs)
#pragma unroll
      for (int i = 0; i < 4; ++i) {
        int r = rs * 16 + lhi * 4 + i;
        pml[slot * 64 + r]      = m_r[rs][i];
        pml[slot * 64 + 32 + r] = l_r[rs][i];
      }
  }
}

// ---------------------------------------------------------------------------
// Kernel 3: merge up to 4 KV-chunk partials. Grid 512 = 64 j x 8 b, 256 thr.
// ---------------------------------------------------------------------------
__global__ __launch_bounds__(256) void combine_kernel(const float* __restrict__ po,
                                                      const float* __restrict__ pml,
                                                      float* __restrict__ out) {
  const int b = blockIdx.x & 7, j = blockIdx.x >> 3;
  const int nu = (j >> 4) + 1;
  const int s0 = ((0)   + 63 - j) * 8 + b;
  const int s1 = ((64)  + 63 - j) * 8 + b;
  const int s2 = ((112) + 63 - j) * 8 + b;
  const int s3 = ((144) + 63 - j) * 8 + b;
  float* og = out + ((size_t)b * 2048 + j * 32) * 64;
#pragma unroll
  for (int k = 0; k < 8; ++k) {
    int e = k * 256 + threadIdx.x;
    int r = e >> 6;
    float M = pml[s0 * 64 + r];
    if (nu > 1) M = fmaxf(M, pml[s1 * 64 + r]);
    if (nu > 2) M = fmaxf(M, pml[s2 * 64 + r]);
    if (nu > 3) M = fmaxf(M, pml[s3 * 64 + r]);
    float num, den;
    {
      float a = __expf(pml[s0 * 64 + r] - M);
      num = po[(size_t)s0 * 2048 + e] * a;
      den = pml[s0 * 64 + 32 + r] * a;
    }
    if (nu > 1) {
      float a = __expf(pml[s1 * 64 + r] - M);
      num += po[(size_t)s1 * 2048 + e] * a;
      den += pml[s1 * 64 + 32 + r] * a;
    }
    if (nu > 2) {
      float a = __expf(pml[s2 * 64 + r] - M);
      num += po[(size_t)s2 * 2048 + e] * a;
      den += pml[s2 * 64 + 32 + r] * a;
    }
    if (nu > 3) {
      float a = __expf(pml[s3 * 64 + r] - M);
      num += po[(size_t)s3 * 2048 + e] * a;
      den += pml[s3 * 64 + 32 + r] * a;
    }
    og[e] = num / den;
  }
}

// ---------------------------------------------------------------------------
extern "C" void kernel_launch(void* const* d_in, const int* in_sizes, int n_in,
                              void* d_out, int out_size, void* d_ws, size_t ws_size,
                              hipStream_t stream) {
  const float* x  = (const float*)d_in[0];
  const float* Wk = (const float*)d_in[1];
  const float* Wq = (const float*)d_in[2];
  const float* Wv = (const float*)d_in[3];
  float* out = (float*)d_out;

  const size_t QKV = (size_t)Bc * Tc * 64;       // 1,048,576 elems
  char* w = (char*)d_ws;
  u16* kb_h = (u16*)w;               w += QKV * 2;
  u16* kb_l = (u16*)w;               w += QKV * 2;
  u16* qb_h = (u16*)w;               w += QKV * 2;
  u16* qb_l = (u16*)w;               w += QKV * 2;
  u16* vt   = (u16*)w;               w += QKV * 2;
  u16* wtf  = (u16*)w;               w += (size_t)192 * 1024 * 2;
  float* po = (float*)w;             w += (size_t)1280 * 2048 * 4;
  float* pml = (float*)w;            w += (size_t)1280 * 64 * 4;

  build_wt<<<768, 256, 0, stream>>>(Wk, Wq, Wv, wtf);
  proj_kernel<<<512, 256, 0, stream>>>(x, wtf, kb_h, kb_l, qb_h, qb_l, vt);
  attn_kernel<<<1280, 64, 0, stream>>>(qb_h, qb_l, kb_h, kb_l, vt, po, pml);
  combine_kernel<<<512, 256, 0, stream>>>(po, pml, out);
}

// Round 10
// 87.636 us; speedup vs baseline: 1.5737x; 1.1191x over previous
//
#include <hip/hip_runtime.h>
#include <hip/hip_bf16.h>

typedef unsigned short u16;
typedef __bf16 bf16x8 __attribute__((ext_vector_type(8)));
typedef _Float16 f16x8 __attribute__((ext_vector_type(8)));
typedef float f32x4 __attribute__((ext_vector_type(4)));

#define DEVINL __device__ __forceinline__

static constexpr int Bc = 8, Tc = 2048;

DEVINL u16 f2bf(float f) {
  unsigned u = __builtin_bit_cast(unsigned, f);
  unsigned r = u + 0x7fffu + ((u >> 16) & 1u);   // RNE
  return (u16)(r >> 16);
}
DEVINL float bf2f(u16 h) {
  unsigned u = ((unsigned)h) << 16;
  return __builtin_bit_cast(float, u);
}

// swizzled LDS read of 8 contiguous 16-bit elems from a [R][64] tile.
DEVINL bf16x8 lds_ld8(const u16* p, int row, int col) {
  return *(const bf16x8*)&p[row * 64 + (col ^ ((row & 7) << 3))];
}
DEVINL f16x8 lds_ld8h(const u16* p, int row, int col) {
  return *(const f16x8*)&p[row * 64 + (col ^ ((row & 7) << 3))];
}

// ---------------------------------------------------------------------------
// Kernel 0: pre-swizzled wt_s[ch][c][kc'] = f16(W_{c/64}[ch*64 + (kc' ^
// ((c&7)<<3))][c%64]).  Linear global order == desired LDS image, so
// global_load_lds (linear DMA) lands the swizzle for conflict-free b128 reads.
// NOTE: chunk stride 12288 = 192*64 is NOT a power of two -> use / and %
// (R9 bug: idx>>13 / &8191 scrambled the table and read W out of bounds).
// ---------------------------------------------------------------------------
__global__ __launch_bounds__(256) void build_wt(const float* __restrict__ Wk,
                                                const float* __restrict__ Wq,
                                                const float* __restrict__ Wv,
                                                u16* __restrict__ wt_s) {
  int idx = blockIdx.x * 256 + threadIdx.x;      // 16*192*64 = 196608
  int ch = idx / 12288;
  int rem = idx - ch * 12288;
  int c = rem >> 6, kc = rem & 63;
  int k = ch * 64 + (kc ^ ((c & 7) << 3));
  const float* W = (c < 64) ? Wk : (c < 128 ? Wq : Wv);
  _Float16 h = (_Float16)W[k * 64 + (c & 63)];
  wt_s[idx] = __builtin_bit_cast(u16, h);
}

// ---------------------------------------------------------------------------
// Kernel 1: fused QKV projection, f16-single, BOTH operands LDS-staged.
// 512 blocks x 256 thr (4 waves; wave = 48 cols x 32 rows).
// Per K-step: issue global_load_lds for NEXT wt chunk (24KB) + NT-load NEXT
// x chunk to regs -> COMPUTE current from LDS -> cvt/store x -> barrier.
// wt prefetch latency hides under COMPUTE; barrier vmcnt drain finds it done.
// q,k written hi/lo bf16; V TRANSPOSED [b][d][t] bf16.
// ---------------------------------------------------------------------------
__global__ __launch_bounds__(256, 2) void proj_kernel(const float* __restrict__ x,
                                                      const u16* __restrict__ wt_s,
                                                      u16* __restrict__ kb_h, u16* __restrict__ kb_l,
                                                      u16* __restrict__ qb_h, u16* __restrict__ qb_l,
                                                      u16* __restrict__ vt) {
  __shared__ u16 wl[2][192 * 64];        // 48KB  wt chunk dbuf (pre-swizzled)
  __shared__ u16 xl[2][32 * 64];         // 8KB   x chunk dbuf (swizzled)
  const int t = threadIdx.x;
  const int w = t >> 6, lane = t & 63;
  const int l16 = lane & 15, lhi = lane >> 4;
  const int rb = blockIdx.x * 32;
  const int cb = w * 48;
  const int sr = t >> 3, sc = (t & 7) * 8;
  const f32x4* xrow = (const f32x4*)(x + (size_t)(rb + sr) * 1024 + sc);

  f32x4 acc[2][3];
#pragma unroll
  for (int a = 0; a < 2; ++a)
#pragma unroll
    for (int c = 0; c < 3; ++c) acc[a][c] = (f32x4){0.f, 0.f, 0.f, 0.f};

  // stage wt chunk CH into wl[S]: 24KB = 256 thr x 6 x 16B, linear DMA
#define STAGE_WT(S, CH)                                                        \
  {                                                                            \
    const u16* src = wt_s + (size_t)(CH) * 12288 + t * 8;                      \
    u16* dst = &wl[S][t * 8];                                                  \
    _Pragma("unroll") for (int i = 0; i < 6; ++i)                              \
      __builtin_amdgcn_global_load_lds(                                        \
          (const __attribute__((address_space(1))) unsigned int*)(src + i * 2048), \
          (__attribute__((address_space(3))) unsigned int*)(dst + i * 2048),   \
          16, 0, 0);                                                           \
  }

#define CVT_STORE(S, F0, F1)                                                   \
  {                                                                            \
    union { _Float16 h[8]; uint4 v; } p_;                                      \
    _Pragma("unroll") for (int j = 0; j < 4; ++j) {                            \
      p_.h[j] = (_Float16)(F0)[j];                                             \
      p_.h[4 + j] = (_Float16)(F1)[j];                                         \
    }                                                                          \
    *(uint4*)&xl[S][sr * 64 + (sc ^ ((sr & 7) << 3))] = p_.v;                  \
  }

  // B-frag from staged wt: row c (0..191), col base kk*32+lhi*8, XOR swizzle
#define COMPUTE(S)                                                             \
  _Pragma("unroll") for (int kk = 0; kk < 2; ++kk) {                           \
    f16x8 a0 = lds_ld8h(xl[S], l16, kk * 32 + lhi * 8);                        \
    f16x8 a1 = lds_ld8h(xl[S], 16 + l16, kk * 32 + lhi * 8);                   \
    _Pragma("unroll") for (int tc = 0; tc < 3; ++tc) {                         \
      int c_ = cb + tc * 16 + l16;                                             \
      f16x8 bf = *(const f16x8*)&wl[S][c_ * 64 + ((kk * 32 + lhi * 8) ^ ((c_ & 7) << 3))]; \
      acc[0][tc] = __builtin_amdgcn_mfma_f32_16x16x32_f16(a0, bf, acc[0][tc], 0, 0, 0); \
      acc[1][tc] = __builtin_amdgcn_mfma_f32_16x16x32_f16(a1, bf, acc[1][tc], 0, 0, 0); \
    }                                                                          \
  }

  // prologue: stage chunk 0 (wt + x), one barrier
  STAGE_WT(0, 0);
  {
    f32x4 A0 = __builtin_nontemporal_load(xrow);
    f32x4 A1 = __builtin_nontemporal_load(xrow + 1);
    CVT_STORE(0, A0, A1);
  }
  __syncthreads();

#pragma unroll 2
  for (int ch = 0; ch < 16; ++ch) {
    const int cur = ch & 1, nxt = cur ^ 1;
    f32x4 A0, A1;
    if (ch + 1 < 16) {
      STAGE_WT(nxt, ch + 1);             // prefetch next wt -> other buffer
      A0 = __builtin_nontemporal_load(xrow + (ch + 1) * 16);
      A1 = __builtin_nontemporal_load(xrow + (ch + 1) * 16 + 1);
    }
    COMPUTE(cur);                        // current chunk from LDS
    if (ch + 1 < 16) {
      CVT_STORE(nxt, A0, A1);
      __syncthreads();                   // drains wt DMA + x store for nxt
    }
  }
#undef STAGE_WT
#undef CVT_STORE
#undef COMPUTE

  // epilogue
#pragma unroll
  for (int ri = 0; ri < 2; ++ri) {
#pragma unroll
    for (int tc = 0; tc < 3; ++tc) {
      int gc = cb + tc * 16 + l16;
      int cc = gc & 63;
      int row = rb + ri * 16 + lhi * 4;
#pragma unroll
      for (int i = 0; i < 4; ++i) {
        float f = acc[ri][tc][i];
        int r = row + i;
        u16 h = f2bf(f);
        if (gc < 64) {
          size_t off = (size_t)r * 64 + cc;
          kb_h[off] = h; kb_l[off] = f2bf(f - bf2f(h));
        } else if (gc < 128) {
          size_t off = (size_t)r * 64 + cc;
          qb_h[off] = h; qb_l[off] = f2bf(f - bf2f(h));
        } else {
          int bb = r >> 11, tp = r & 2047;
          vt[((size_t)bb * 64 + cc) * 2048 + tp] = h;
        }
      }
    }
  }
}

// ---------------------------------------------------------------------------
// Kernel 2: causal flash attention, barrier-free, KV-chunk 512.
// (exact R6/R8-measured version: 160 units/batch x 8 = 1280 blocks x 1 wave)
// ---------------------------------------------------------------------------
__global__ __launch_bounds__(64, 2) void attn_kernel(const u16* __restrict__ qb_h,
                                                     const u16* __restrict__ qb_l,
                                                     const u16* __restrict__ kb_h,
                                                     const u16* __restrict__ kb_l,
                                                     const u16* __restrict__ vt,
                                                     float* __restrict__ po,
                                                     float* __restrict__ pml) {
  __shared__ u16 p_l[2][1024];           // per-rowset P tile (16x64, swizzled)

  const int t = threadIdx.x;             // one wave
  const int l16 = t & 15, lhi = t >> 4;
  const int u = blockIdx.x >> 3, b = blockIdx.x & 7;

  int j, c;
  if (u < 64)       { c = 0; j = 63 - u; }
  else if (u < 112) { c = 1; j = 63 - (u - 64); }
  else if (u < 144) { c = 2; j = 63 - (u - 112); }
  else              { c = 3; j = 63 - (u - 144); }

  const int kv0 = c << 9;
  const int prefix = j * 32 + 32;
  const int kv_end = (prefix < kv0 + 512) ? prefix : (kv0 + 512);
  const int nt = (kv_end - kv0 + 63) >> 6;
  const bool diag = (kv_end == prefix);

  const size_t qrow = (size_t)b * 2048 + j * 32;

  // Q fragments straight from global: lane l16 = q row, 16B contiguous cols
  bf16x8 aqh[2][2], aql[2][2];           // [rowset][kk]
#pragma unroll
  for (int rs = 0; rs < 2; ++rs)
#pragma unroll
    for (int kk = 0; kk < 2; ++kk) {
      size_t qo = (qrow + rs * 16 + l16) * 64 + kk * 32 + lhi * 8;
      aqh[rs][kk] = *(const bf16x8*)(qb_h + qo);
      aql[rs][kk] = *(const bf16x8*)(qb_l + qo);
    }

  f32x4 o[2][4];
  float m_r[2][4], l_r[2][4];
#pragma unroll
  for (int rs = 0; rs < 2; ++rs)
#pragma unroll
    for (int i = 0; i < 4; ++i) {
      o[rs][i] = (f32x4){0.f, 0.f, 0.f, 0.f};
      m_r[rs][i] = -3.0e38f; l_r[rs][i] = 0.f;
    }

  for (int tk = 0; tk < nt; ++tk) {
    const int kvb = kv0 + tk * 64;
    const size_t kbase = ((size_t)b * 2048 + kvb) * 64;

    // S = Q K^T: K frags loaded per-t4 (transient regs)
    f32x4 sa[2][4];
#pragma unroll
    for (int t4 = 0; t4 < 4; ++t4) {
      size_t kr = kbase + (size_t)(t4 * 16 + l16) * 64 + lhi * 8;
      bf16x8 kh0 = *(const bf16x8*)(kb_h + kr);
      bf16x8 kh1 = *(const bf16x8*)(kb_h + kr + 32);
      bf16x8 kl0 = *(const bf16x8*)(kb_l + kr);
      bf16x8 kl1 = *(const bf16x8*)(kb_l + kr + 32);
#pragma unroll
      for (int rs = 0; rs < 2; ++rs) {
        f32x4 s = (f32x4){0.f, 0.f, 0.f, 0.f};
        s = __builtin_amdgcn_mfma_f32_16x16x32_bf16(aqh[rs][0], kh0, s, 0, 0, 0);
        s = __builtin_amdgcn_mfma_f32_16x16x32_bf16(aqh[rs][0], kl0, s, 0, 0, 0);
        s = __builtin_amdgcn_mfma_f32_16x16x32_bf16(aql[rs][0], kh0, s, 0, 0, 0);
        s = __builtin_amdgcn_mfma_f32_16x16x32_bf16(aqh[rs][1], kh1, s, 0, 0, 0);
        s = __builtin_amdgcn_mfma_f32_16x16x32_bf16(aqh[rs][1], kl1, s, 0, 0, 0);
        s = __builtin_amdgcn_mfma_f32_16x16x32_bf16(aql[rs][1], kh1, s, 0, 0, 0);
        sa[rs][t4] = s;
      }
    }

    // V fragment loads (consumed in PV; issued before softmax to hide latency)
    bf16x8 vv[4][2];
#pragma unroll
    for (int t4 = 0; t4 < 4; ++t4) {
      size_t vr = ((size_t)b * 64 + t4 * 16 + l16) * 2048 + kvb + lhi * 8;
      vv[t4][0] = *(const bf16x8*)(vt + vr);
      vv[t4][1] = *(const bf16x8*)(vt + vr + 32);
    }

    // causal mask (global indices); only the diagonal unit's last tile
    if (diag && tk == nt - 1) {
#pragma unroll
      for (int rs = 0; rs < 2; ++rs) {
        int qr = j * 32 + rs * 16 + lhi * 4;
#pragma unroll
        for (int t4 = 0; t4 < 4; ++t4) {
          int col = kvb + t4 * 16 + l16;
#pragma unroll
          for (int i = 0; i < 4; ++i)
            if (col > qr + i) sa[rs][t4][i] = -1e30f;
        }
      }
    }

#pragma unroll
    for (int rs = 0; rs < 2; ++rs) {
      // online softmax
      float pf[4][4];
#pragma unroll
      for (int i = 0; i < 4; ++i) {
        float tm = fmaxf(fmaxf(sa[rs][0][i], sa[rs][1][i]), fmaxf(sa[rs][2][i], sa[rs][3][i]));
#pragma unroll
        for (int d = 1; d < 16; d <<= 1) tm = fmaxf(tm, __shfl_xor(tm, d));
        float mn = fmaxf(m_r[rs][i], tm);
        float scl = __expf(m_r[rs][i] - mn);
        float rsum = 0.f;
#pragma unroll
        for (int t4 = 0; t4 < 4; ++t4) {
          float p = __expf(sa[rs][t4][i] - mn);
          pf[t4][i] = p;
          rsum += p;
        }
#pragma unroll
        for (int d = 1; d < 16; d <<= 1) rsum += __shfl_xor(rsum, d);
        l_r[rs][i] = l_r[rs][i] * scl + rsum;
        m_r[rs][i] = mn;
#pragma unroll
        for (int t4 = 0; t4 < 4; ++t4) o[rs][t4][i] *= scl;
      }

      // P -> bf16 -> per-rowset LDS (swizzled, wave-private, no barrier)
      u16* pw = (u16*)p_l[rs];
#pragma unroll
      for (int i = 0; i < 4; ++i) {
        int rr = lhi * 4 + i;
#pragma unroll
        for (int t4 = 0; t4 < 4; ++t4) {
          int col = t4 * 16 + l16;
          pw[rr * 64 + (col ^ ((rr & 7) << 3))] = f2bf(pf[t4][i]);
        }
      }
      // PV
#pragma unroll
      for (int kk = 0; kk < 2; ++kk) {
        bf16x8 ap = lds_ld8(pw, l16, kk * 32 + lhi * 8);
#pragma unroll
        for (int t4 = 0; t4 < 4; ++t4)
          o[rs][t4] = __builtin_amdgcn_mfma_f32_16x16x32_bf16(ap, vv[t4][kk], o[rs][t4], 0, 0, 0);
      }
    }
  }

  // write partials (all units)
  const int slot = blockIdx.x;
  float* pou = po + (size_t)slot * 2048;
#pragma unroll
  for (int rs = 0; rs < 2; ++rs)
#pragma unroll
    for (int t4 = 0; t4 < 4; ++t4) {
      int col = t4 * 16 + l16;
#pragma unroll
      for (int i = 0; i < 4; ++i)
        pou[(rs * 16 + lhi * 4 + i) * 64 + col] = o[rs][t4][i];
    }
  if (l16 == 0) {
#pragma unroll
    for (int rs = 0; rs < 2; ++rs)
#pragma unroll
      for (int i = 0; i < 4; ++i) {
        int r = rs * 16 + lhi * 4 + i;
        pml[slot * 64 + r]      = m_r[rs][i];
        pml[slot * 64 + 32 + r] = l_r[rs][i];
      }
  }
}

// ---------------------------------------------------------------------------
// Kernel 3: merge up to 4 KV-chunk partials. Grid 512 = 64 j x 8 b, 256 thr.
// ---------------------------------------------------------------------------
__global__ __launch_bounds__(256) void combine_kernel(const float* __restrict__ po,
                                                      const float* __restrict__ pml,
                                                      float* __restrict__ out) {
  const int b = blockIdx.x & 7, j = blockIdx.x >> 3;
  const int nu = (j >> 4) + 1;
  const int s0 = ((0)   + 63 - j) * 8 + b;
  const int s1 = ((64)  + 63 - j) * 8 + b;
  const int s2 = ((112) + 63 - j) * 8 + b;
  const int s3 = ((144) + 63 - j) * 8 + b;
  float* og = out + ((size_t)b * 2048 + j * 32) * 64;
#pragma unroll
  for (int k = 0; k < 8; ++k) {
    int e = k * 256 + threadIdx.x;
    int r = e >> 6;
    float M = pml[s0 * 64 + r];
    if (nu > 1) M = fmaxf(M, pml[s1 * 64 + r]);
    if (nu > 2) M = fmaxf(M, pml[s2 * 64 + r]);
    if (nu > 3) M = fmaxf(M, pml[s3 * 64 + r]);
    float num, den;
    {
      float a = __expf(pml[s0 * 64 + r] - M);
      num = po[(size_t)s0 * 2048 + e] * a;
      den = pml[s0 * 64 + 32 + r] * a;
    }
    if (nu > 1) {
      float a = __expf(pml[s1 * 64 + r] - M);
      num += po[(size_t)s1 * 2048 + e] * a;
      den += pml[s1 * 64 + 32 + r] * a;
    }
    if (nu > 2) {
      float a = __expf(pml[s2 * 64 + r] - M);
      num += po[(size_t)s2 * 2048 + e] * a;
      den += pml[s2 * 64 + 32 + r] * a;
    }
    if (nu > 3) {
      float a = __expf(pml[s3 * 64 + r] - M);
      num += po[(size_t)s3 * 2048 + e] * a;
      den += pml[s3 * 64 + 32 + r] * a;
    }
    og[e] = num / den;
  }
}

// ---------------------------------------------------------------------------
extern "C" void kernel_launch(void* const* d_in, const int* in_sizes, int n_in,
                              void* d_out, int out_size, void* d_ws, size_t ws_size,
                              hipStream_t stream) {
  const float* x  = (const float*)d_in[0];
  const float* Wk = (const float*)d_in[1];
  const float* Wq = (const float*)d_in[2];
  const float* Wv = (const float*)d_in[3];
  float* out = (float*)d_out;

  const size_t QKV = (size_t)Bc * Tc * 64;       // 1,048,576 elems
  char* w = (char*)d_ws;
  u16* kb_h = (u16*)w;               w += QKV * 2;
  u16* kb_l = (u16*)w;               w += QKV * 2;
  u16* qb_h = (u16*)w;               w += QKV * 2;
  u16* qb_l = (u16*)w;               w += QKV * 2;
  u16* vt   = (u16*)w;               w += QKV * 2;
  u16* wt_s = (u16*)w;               w += (size_t)16 * 192 * 64 * 2;
  float* po = (float*)w;             w += (size_t)1280 * 2048 * 4;
  float* pml = (float*)w;            w += (size_t)1280 * 64 * 4;

  build_wt<<<768, 256, 0, stream>>>(Wk, Wq, Wv, wt_s);
  proj_kernel<<<512, 256, 0, stream>>>(x, wt_s, kb_h, kb_l, qb_h, qb_l, vt);
  attn_kernel<<<1280, 64, 0, stream>>>(qb_h, qb_l, kb_h, kb_l, vt, po, pml);
  combine_kernel<<<512, 256, 0, stream>>>(po, pml, out);
}